// Round 11
// baseline (264.545 us; speedup 1.0000x reference)
//
#include <hip/hip_runtime.h>
#include <hip/hip_bf16.h>
#include <stdint.h>

#define B_ 32
#define T_ 1024
#define C_ 768
#define H_ 64

typedef float f32x4 __attribute__((ext_vector_type(4)));
typedef short bf16x8 __attribute__((ext_vector_type(8)));

static __device__ __forceinline__ unsigned short f2bf(float f) {
    uint32_t u = __float_as_uint(f);
    u += 0x7fffu + ((u >> 16) & 1u);   // RNE
    return (unsigned short)(u >> 16);
}

// ---------------- Kernel A0: pack Wq|Wk|Wv (fp32) -> W_all[192][768] bf16 ----------------
__global__ void wpack(const float* __restrict__ Wq, const float* __restrict__ Wk,
                      const float* __restrict__ Wv, unsigned short* __restrict__ Wall) {
    int i = blockIdx.x * 256 + threadIdx.x;      // one float4 per thread
    int base = i * 4;
    if (base >= 192 * 768) return;
    int r = base / 768, c = base % 768;
    const float* src = (r < 64) ? (Wq + r * 768 + c)
                     : (r < 128) ? (Wk + (r - 64) * 768 + c)
                                 : (Wv + (r - 128) * 768 + c);
    float4 v = *(const float4*)src;
    ushort4 o;
    o.x = f2bf(v.x); o.y = f2bf(v.y); o.z = f2bf(v.z); o.w = f2bf(v.w);
    *(ushort4*)(Wall + base) = o;
}

// ---------------- Kernel A1: QKV projection, BARRIER-FREE ----------------
// No __syncthreads in the k-loop: each wave owns 16 rows x 192 cols. A-frags read
// directly from fp32 x (coalesced: 16 rows x 128B per wave-instr) + in-loop cvt;
// B-frags read directly from Wall (288 KB, L1/L2-resident, re-read by all waves).
// Compiler can now software-pipeline loads across iterations (no vmcnt(0) drain).
__global__ __launch_bounds__(256)
void qkv_proj(const float* __restrict__ x, const unsigned short* __restrict__ Wall,
              unsigned short* __restrict__ qb, unsigned short* __restrict__ kb,
              unsigned short* __restrict__ vt) {
    __shared__ unsigned short tr[4][16 * 20];    // per-wave transpose patch (wave-private)

    const int tid = threadIdx.x;
    const int lane = tid & 63, w = tid >> 6;
    const int rowbase = blockIdx.x * 64;         // block covers rows rowbase..+63 of [B*T]
    const int fr = lane & 15, fg = lane >> 4;
    const int myrow = rowbase + w * 16 + fr;     // this lane's x row (A-frag row)

    const float*          xp  = x    + (size_t)myrow * 768 + fg * 8;
    const unsigned short* wp0 = Wall + (size_t)fr * 768 + fg * 8;

    f32x4 acc[12] = {};

    for (int ks = 0; ks < 768; ks += 32) {
        float4 xa = *(const float4*)(xp + ks);
        float4 xb = *(const float4*)(xp + ks + 4);
        bf16x8 af;
        af[0] = (short)f2bf(xa.x); af[1] = (short)f2bf(xa.y);
        af[2] = (short)f2bf(xa.z); af[3] = (short)f2bf(xa.w);
        af[4] = (short)f2bf(xb.x); af[5] = (short)f2bf(xb.y);
        af[6] = (short)f2bf(xb.z); af[7] = (short)f2bf(xb.w);
#pragma unroll
        for (int j = 0; j < 12; j++) {
            bf16x8 bf = *(const bf16x8*)(wp0 + (size_t)j * 16 * 768 + ks);
            acc[j] = __builtin_amdgcn_mfma_f32_16x16x32_bf16(af, bf, acc[j], 0, 0, 0);
        }
    }

    // epilogue: C-frag (m89 layout) col=lane&15, row=(lane>>4)*4+reg. Wave-private.
    const int b  = rowbase >> 10;
    const int t0 = (rowbase & 1023) + w * 16;    // wave's token base
    unsigned short* trp = &tr[w][0];
#pragma unroll
    for (int j = 0; j < 12; j++) {
        const int nc = j * 16;                   // global col 0..191
        if (nc < 128) {
            // q or k: [T][64] layout -> transpose via wave-private LDS patch
            unsigned short* dstb = (nc < 64) ? qb : kb;
            const int col = nc & 63;
#pragma unroll
            for (int r = 0; r < 4; r++)
                trp[(fg * 4 + r) * 20 + fr] = f2bf(acc[j][r]);
            int row = lane >> 2, seg = lane & 3; // same-wave DS in-order -> safe
            ushort4 rv = *(const ushort4*)(trp + row * 20 + seg * 4);
            *(ushort4*)(dstb + (size_t)(b * 1024 + t0 + row) * 64 + col + seg * 4) = rv;
        } else {
            // v: [64][T] transposed layout is the natural C-frag store
            const int h = nc - 128 + fr;
            ushort4 o;
            o.x = f2bf(acc[j][0]); o.y = f2bf(acc[j][1]);
            o.z = f2bf(acc[j][2]); o.w = f2bf(acc[j][3]);
            *(ushort4*)(vt + (size_t)(b * 64 + h) * 1024 + t0 + fg * 4) = o;
        }
    }
}

// ---------------- Kernel B: causal flash attention via MFMA, BARRIER-FREE ----------------
// 4 waves/block but fully independent (no __syncthreads). K/V fragments read directly
// from global (L2-resident: 256 KB per batch, heavily re-read). Only the wave-private
// P^T patch uses LDS. Same math as the R6 passing kernel.
__global__ __launch_bounds__(256)
void attn_mfma(const unsigned short* __restrict__ qbuf, const unsigned short* __restrict__ kbuf,
               const unsigned short* __restrict__ vtb, float* __restrict__ out) {
    __shared__ unsigned short ldsP[4][16 * 72];  // per-wave P^T patch [q][k], stride 72

    const int tid  = threadIdx.x;
    const int lane = tid & 63, w = tid >> 6;
    const int q16 = lane & 15, g = lane >> 4;

    // load-balance pairing: concurrent blocks get complementary diagonal cost (bx, 15-bx)
    const int fid = blockIdx.x;
    const int p = fid & 255, half = fid >> 8;
    const int bx = half ? (15 - (p & 15)) : (p & 15);
    const int b  = (p >> 4) + (half << 4);

    const int qrow0 = bx * 64 + w * 16;

    const unsigned short* qp = qbuf + ((size_t)(b * 1024 + qrow0 + q16) << 6);
    bf16x8 qfrag[2];
    qfrag[0] = *(const bf16x8*)(qp + (g << 3));
    qfrag[1] = *(const bf16x8*)(qp + 32 + (g << 3));

    f32x4 accO[4] = {};
    float m_run = -INFINITY, l_run = 0.f;

    for (int ci = 0; ci <= bx; ci++) {
        const int kbase = ci << 6;

        // ---- QK^T: S^T[k][q], A-frags (K rows) straight from global/L2 ----
        f32x4 accS[4] = {};
#pragma unroll
        for (int t = 0; t < 4; t++) {
            const unsigned short* kr = kbuf + ((size_t)(b * 1024 + kbase + (t << 4) + q16) << 6);
#pragma unroll
            for (int s = 0; s < 2; s++) {
                bf16x8 af = *(const bf16x8*)(kr + (s << 5) + (g << 3));
                accS[t] = __builtin_amdgcn_mfma_f32_16x16x32_bf16(af, qfrag[s], accS[t], 0, 0, 0);
            }
        }

        // ---- scale + causal mask + chunk max (C-frag regs) ----
        const bool diag = (ci == bx);
        const int qlim = (w << 4) + q16;
        float mloc = -INFINITY;
#pragma unroll
        for (int t = 0; t < 4; t++)
#pragma unroll
            for (int r = 0; r < 4; r++) {
                float s = accS[t][r] * 0.125f;   // 1/sqrt(64)
                int kl = (t << 4) + (g << 2) + r;
                if (diag && kl > qlim) s = -INFINITY;
                accS[t][r] = s;
                mloc = fmaxf(mloc, s);
            }
        mloc = fmaxf(mloc, __shfl_xor(mloc, 16, 64));
        mloc = fmaxf(mloc, __shfl_xor(mloc, 32, 64));
        const float m_new = fmaxf(m_run, mloc);
        const float alpha = __expf(m_run - m_new);   // first chunk: exp(-inf)=0
        m_run = m_new;

        // ---- P = exp(S-m), pack bf16, write P^T patch [q][k] (wave-private) ----
        unsigned short* pl = &ldsP[w][0];
        float lloc = 0.f;
#pragma unroll
        for (int t = 0; t < 4; t++) {
            float p0 = __expf(accS[t][0] - m_new);
            float p1 = __expf(accS[t][1] - m_new);
            float p2 = __expf(accS[t][2] - m_new);
            float p3 = __expf(accS[t][3] - m_new);
            lloc += (p0 + p1) + (p2 + p3);
            uint2 pk;
            pk.x = (uint32_t)f2bf(p0) | ((uint32_t)f2bf(p1) << 16);
            pk.y = (uint32_t)f2bf(p2) | ((uint32_t)f2bf(p3) << 16);
            *(uint2*)(pl + q16 * 72 + (t << 4) + (g << 2)) = pk;   // keys 16t+4g..+3, col q16
        }
        lloc += __shfl_xor(lloc, 16, 64);
        lloc += __shfl_xor(lloc, 32, 64);
        l_run = l_run * alpha + lloc;

        // ---- rescale O^T, then O^T += V^T · P^T (V-frags straight from global/L2) ----
#pragma unroll
        for (int t = 0; t < 4; t++) accO[t] *= alpha;

        bf16x8 pf0 = *(const bf16x8*)(pl + q16 * 72 + (g << 3));
        bf16x8 pf1 = *(const bf16x8*)(pl + q16 * 72 + 32 + (g << 3));
#pragma unroll
        for (int tp = 0; tp < 4; tp++) {
            const unsigned short* vr = vtb + ((size_t)(b * 64 + (tp << 4) + q16) << 10) + kbase;
            bf16x8 af0 = *(const bf16x8*)(vr + (g << 3));
            accO[tp] = __builtin_amdgcn_mfma_f32_16x16x32_bf16(af0, pf0, accO[tp], 0, 0, 0);
            bf16x8 af1 = *(const bf16x8*)(vr + 32 + (g << 3));
            accO[tp] = __builtin_amdgcn_mfma_f32_16x16x32_bf16(af1, pf1, accO[tp], 0, 0, 0);
        }
    }

    // ---- epilogue: out[b][t][h] = O^T[h][q]/l ----
    const float inv = 1.0f / l_run;
    float* op = out + ((size_t)(b * 1024 + qrow0 + q16) << 6);
#pragma unroll
    for (int tp = 0; tp < 4; tp++) {
        float4 o4;
        o4.x = accO[tp][0] * inv; o4.y = accO[tp][1] * inv;
        o4.z = accO[tp][2] * inv; o4.w = accO[tp][3] * inv;
        *(float4*)(op + (tp << 4) + (g << 2)) = o4;    // h = 16tp + 4g .. +3
    }
}

// ---------------- launch ----------------
extern "C" void kernel_launch(void* const* d_in, const int* in_sizes, int n_in,
                              void* d_out, int out_size, void* d_ws, size_t ws_size,
                              hipStream_t stream) {
    const float* x  = (const float*)d_in[0];
    const float* Wq = (const float*)d_in[1];
    const float* Wk = (const float*)d_in[2];
    const float* Wv = (const float*)d_in[3];

    unsigned short* Wall = (unsigned short*)d_ws;              // 192*768 bf16
    unsigned short* qbuf = Wall + 192 * 768;                   // [B][T][64] bf16
    unsigned short* kbuf = qbuf + (size_t)B_ * T_ * H_;        // [B][T][64] bf16
    unsigned short* vtb  = kbuf + (size_t)B_ * T_ * H_;        // [B][64][T] bf16
    float* out = (float*)d_out;

    wpack<<<144, 256, 0, stream>>>(Wq, Wk, Wv, Wall);
    qkv_proj<<<512, 256, 0, stream>>>(x, Wall, qbuf, kbuf, vtb);
    attn_mfma<<<512, 256, 0, stream>>>(qbuf, kbuf, vtb, out);
}